// Round 1
// baseline (96.324 us; speedup 1.0000x reference)
//
#include <hip/hip_runtime.h>

// Problem shape (fixed by the reference):
//   x:     [B,S]   f32
//   W1:    [B,S,S] f32   (256 MiB)
//   delta, eta, theta: [S] f32
// Outputs (concatenated in d_out): y [B,S] f32, then W1_new [B,S,S] f32.
//
// y[b,i]      = sigmoid(eta[i]) * relu6(sigmoid(theta[i])*x[b,i] + sum_j W1[b,i,j]*x[b,j])
// W1n[b,i,j]  = y[b,i]*x[b,j] - (1 - sigmoid(delta[i])) * W1[b,i,j]
//
// Strategy: one 64-lane wave per (b,i) row. Row (1024 f32) held in 16 VGPRs/lane,
// wave shuffle-reduce for the dot, then rewrite the row from registers.
// W1 read once + written once => ~512 MiB HBM traffic, memory-bound.

constexpr int B = 64;
constexpr int S = 1024;
constexpr int ROWS_PER_BLOCK = 4;   // 4 waves * 64 lanes

__global__ __launch_bounds__(256) void fused_fastweight_kernel(
    const float* __restrict__ x,
    const float* __restrict__ W1,
    const float* __restrict__ delta,
    const float* __restrict__ eta,
    const float* __restrict__ theta,
    float* __restrict__ y_out,
    float* __restrict__ W1_out)
{
    const int wave = threadIdx.x >> 6;          // 0..3
    const int lane = threadIdx.x & 63;
    const long long row = (long long)blockIdx.x * ROWS_PER_BLOCK + wave; // 0..B*S-1
    const int b = (int)(row >> 10);             // row / S
    const int i = (int)(row & (S - 1));         // row % S

    const float* __restrict__ w_row = W1 + (size_t)row * S;
    const float* __restrict__ x_row = x + (size_t)b * S;

    // Each lane: columns {lane*4 + k*256 .. +3} for k=0..3 -> fully coalesced float4.
    float4 w[4], xv[4];
    float partial = 0.0f;
#pragma unroll
    for (int k = 0; k < 4; ++k) {
        const int j = lane * 4 + k * 256;
        w[k]  = *reinterpret_cast<const float4*>(w_row + j);
        xv[k] = *reinterpret_cast<const float4*>(x_row + j);
        partial += w[k].x * xv[k].x + w[k].y * xv[k].y
                 + w[k].z * xv[k].z + w[k].w * xv[k].w;
    }

    // Wave-64 butterfly reduction of the dot product.
#pragma unroll
    for (int off = 32; off >= 1; off >>= 1)
        partial += __shfl_xor(partial, off, 64);
    const float dot = partial;   // identical across the wave after butterfly

    // Scalar gated activation for this row.
    const float sig_eta   = 1.0f / (1.0f + expf(-eta[i]));
    const float sig_theta = 1.0f / (1.0f + expf(-theta[i]));
    float pre = sig_theta * x_row[i] + dot;
    pre = fminf(fmaxf(pre, 0.0f), 6.0f);        // relu6
    const float ybi   = sig_eta * pre;
    const float decay = 1.0f - 1.0f / (1.0f + expf(-delta[i]));

    if (lane == 0) y_out[row] = ybi;

    float* __restrict__ out_row = W1_out + (size_t)row * S;
#pragma unroll
    for (int k = 0; k < 4; ++k) {
        const int j = lane * 4 + k * 256;
        float4 o;
        o.x = ybi * xv[k].x - decay * w[k].x;
        o.y = ybi * xv[k].y - decay * w[k].y;
        o.z = ybi * xv[k].z - decay * w[k].z;
        o.w = ybi * xv[k].w - decay * w[k].w;
        *reinterpret_cast<float4*>(out_row + j) = o;
    }
}

extern "C" void kernel_launch(void* const* d_in, const int* in_sizes, int n_in,
                              void* d_out, int out_size, void* d_ws, size_t ws_size,
                              hipStream_t stream) {
    const float* x     = (const float*)d_in[0];
    const float* W1    = (const float*)d_in[1];
    const float* delta = (const float*)d_in[2];
    const float* eta   = (const float*)d_in[3];
    const float* theta = (const float*)d_in[4];

    float* y_out  = (float*)d_out;
    float* W1_out = y_out + (size_t)B * S;      // y first, then W1_new (flat, return order)

    const int total_rows = B * S;               // 65536
    dim3 grid(total_rows / ROWS_PER_BLOCK);     // 16384 blocks
    dim3 block(256);
    fused_fastweight_kernel<<<grid, block, 0, stream>>>(
        x, W1, delta, eta, theta, y_out, W1_out);
}

// Round 2
// 90.510 us; speedup vs baseline: 1.0642x; 1.0642x over previous
//
#include <hip/hip_runtime.h>

// x: [B,S] f32; W1: [B,S,S] f32 (256 MiB); delta/eta/theta: [S] f32.
// Outputs concatenated in d_out: y [B,S] f32, then W1_new [B,S,S] f32.
//
// y[b,i]     = sigmoid(eta[i]) * relu6(sigmoid(theta[i])*x[b,i] + sum_j W1[b,i,j]*x[b,j])
// W1n[b,i,j] = y[b,i]*x[b,j] - (1 - sigmoid(delta[i])) * W1[b,i,j]
//
// One wave per (b,i) row: row held in 16 VGPRs/lane, wave shuffle-reduce for
// the dot, row rewritten from registers. W1 read once + written once.
// R2 change: non-temporal hints on the W1 stream (load + store) so the 512 MB
// zero-reuse stream doesn't thrash L2/L3; x loads stay cached (they're reused
// ~8x per CU from L2).

constexpr int B = 64;
constexpr int S = 1024;
constexpr int ROWS_PER_BLOCK = 4;   // 4 waves * 64 lanes

typedef float f32x4 __attribute__((ext_vector_type(4)));

__global__ __launch_bounds__(256) void fused_fastweight_kernel(
    const float* __restrict__ x,
    const float* __restrict__ W1,
    const float* __restrict__ delta,
    const float* __restrict__ eta,
    const float* __restrict__ theta,
    float* __restrict__ y_out,
    float* __restrict__ W1_out)
{
    const int wave = threadIdx.x >> 6;          // 0..3
    const int lane = threadIdx.x & 63;
    const long long row = (long long)blockIdx.x * ROWS_PER_BLOCK + wave; // 0..B*S-1
    const int b = (int)(row >> 10);             // row / S
    const int i = (int)(row & (S - 1));         // row % S

    const f32x4* __restrict__ w_row =
        reinterpret_cast<const f32x4*>(W1 + (size_t)row * S);
    const float* __restrict__ x_row = x + (size_t)b * S;

    // Each lane: columns {lane*4 + k*256 .. +3} for k=0..3 -> coalesced 1 KiB/wave.
    f32x4 w[4], xv[4];
#pragma unroll
    for (int k = 0; k < 4; ++k) {
        const int j4 = lane + k * 64;           // float4 index within the row
        w[k]  = __builtin_nontemporal_load(w_row + j4);   // streaming: nt hint
        xv[k] = *reinterpret_cast<const f32x4*>(x_row + j4 * 4); // cached: reused
    }
    float partial = 0.0f;
#pragma unroll
    for (int k = 0; k < 4; ++k) {
        partial += w[k].x * xv[k].x + w[k].y * xv[k].y
                 + w[k].z * xv[k].z + w[k].w * xv[k].w;
    }

    // Wave-64 butterfly reduction of the dot product.
#pragma unroll
    for (int off = 32; off >= 1; off >>= 1)
        partial += __shfl_xor(partial, off, 64);
    const float dot = partial;

    // Scalar gated activation for this row.
    const float sig_eta   = 1.0f / (1.0f + expf(-eta[i]));
    const float sig_theta = 1.0f / (1.0f + expf(-theta[i]));
    float pre = sig_theta * x_row[i] + dot;
    pre = fminf(fmaxf(pre, 0.0f), 6.0f);        // relu6
    const float ybi   = sig_eta * pre;
    const float decay = 1.0f - 1.0f / (1.0f + expf(-delta[i]));

    if (lane == 0) y_out[row] = ybi;

    f32x4* __restrict__ out_row =
        reinterpret_cast<f32x4*>(W1_out + (size_t)row * S);
#pragma unroll
    for (int k = 0; k < 4; ++k) {
        const int j4 = lane + k * 64;
        f32x4 o;
        o.x = ybi * xv[k].x - decay * w[k].x;
        o.y = ybi * xv[k].y - decay * w[k].y;
        o.z = ybi * xv[k].z - decay * w[k].z;
        o.w = ybi * xv[k].w - decay * w[k].w;
        __builtin_nontemporal_store(o, out_row + j4);     // streaming: nt hint
    }
}

extern "C" void kernel_launch(void* const* d_in, const int* in_sizes, int n_in,
                              void* d_out, int out_size, void* d_ws, size_t ws_size,
                              hipStream_t stream) {
    const float* x     = (const float*)d_in[0];
    const float* W1    = (const float*)d_in[1];
    const float* delta = (const float*)d_in[2];
    const float* eta   = (const float*)d_in[3];
    const float* theta = (const float*)d_in[4];

    float* y_out  = (float*)d_out;
    float* W1_out = y_out + (size_t)B * S;      // y first, then W1_new (flat, return order)

    const int total_rows = B * S;               // 65536
    dim3 grid(total_rows / ROWS_PER_BLOCK);     // 16384 blocks
    dim3 block(256);
    fused_fastweight_kernel<<<grid, block, 0, stream>>>(
        x, W1, delta, eta, theta, y_out, W1_out);
}